// Round 2
// baseline (978.825 us; speedup 1.0000x reference)
//
#include <hip/hip_runtime.h>
#include <math.h>

#define BSZ 256
#define DIM 1024
#define VOC 50257
#define NL 2
#define NB 8
#define DH 128

typedef __bf16 bf16x8 __attribute__((ext_vector_type(8)));
typedef float  f32x4  __attribute__((ext_vector_type(4)));
typedef unsigned short u16;
typedef u16 u16x8 __attribute__((ext_vector_type(8)));

__device__ __forceinline__ u16 f2bf(float f) {
  unsigned int u = __float_as_uint(f);
  u += 0x7fffu + ((u >> 16) & 1u);   // RNE
  return (u16)(u >> 16);
}
__device__ __forceinline__ float sigm(float x) { return 1.0f / (1.0f + __expf(-x)); }

// ---------------------------------------------------------------------------
// Barrier-free per-wave GEMM: acc[M16][N16] += A(rows m, lda, bf16) *
// B(rows n, ldb, fp32)^T, bf16 MFMA 16x16x32. Fragments loaded DIRECTLY from
// global in MFMA operand layout (A[m=l16][k=quad*8+j], B[n=l16][k=quad*8+j]);
// manual 2-stage register double-buffer keeps next k-step's loads in flight
// during current MFMAs (no LDS, no __syncthreads).
// ---------------------------------------------------------------------------
template<int M16, int N16, int K, bool CLAMPN>
__device__ __forceinline__ void wave_gemm(
    const u16* __restrict__ A, int lda,
    const float* __restrict__ B, int ldb, int nClamp,
    f32x4 (&acc)[M16][N16])
{
  const int lane = threadIdx.x & 63;
  const int quad = lane >> 4;
  const int l16  = lane & 15;

  const u16* aR[M16];
  const float* bR[N16];
#pragma unroll
  for (int mi = 0; mi < M16; ++mi)
    aR[mi] = A + (long)(mi * 16 + l16) * lda + quad * 8;
#pragma unroll
  for (int ni = 0; ni < N16; ++ni) {
    int n = ni * 16 + l16;
    if (CLAMPN) n = n > nClamp ? nClamp : n;   // clamp addr; result discarded
    bR[ni] = B + (long)n * ldb + quad * 8;
  }

  bf16x8 aF[2][M16];
  bf16x8 bF[2][N16];

#define WG_LOAD(kk, buf)                                                  \
  {                                                                       \
    _Pragma("unroll")                                                     \
    for (int ni = 0; ni < N16; ++ni) {                                    \
      float4 v0 = *(const float4*)(bR[ni] + (kk));                        \
      float4 v1 = *(const float4*)(bR[ni] + (kk) + 4);                    \
      u16x8 h;                                                            \
      h[0] = f2bf(v0.x); h[1] = f2bf(v0.y);                               \
      h[2] = f2bf(v0.z); h[3] = f2bf(v0.w);                               \
      h[4] = f2bf(v1.x); h[5] = f2bf(v1.y);                               \
      h[6] = f2bf(v1.z); h[7] = f2bf(v1.w);                               \
      bF[buf][ni] = __builtin_bit_cast(bf16x8, h);                        \
    }                                                                     \
    _Pragma("unroll")                                                     \
    for (int mi = 0; mi < M16; ++mi)                                      \
      aF[buf][mi] = *(const bf16x8*)(aR[mi] + (kk));                      \
  }

#define WG_MM(buf)                                                        \
  {                                                                       \
    _Pragma("unroll")                                                     \
    for (int mi = 0; mi < M16; ++mi)                                      \
      _Pragma("unroll")                                                   \
      for (int ni = 0; ni < N16; ++ni)                                    \
        acc[mi][ni] = __builtin_amdgcn_mfma_f32_16x16x32_bf16(            \
            aF[buf][mi], bF[buf][ni], acc[mi][ni], 0, 0, 0);              \
  }

  WG_LOAD(0, 0);
#pragma unroll 1
  for (int kk = 0; kk < K; kk += 64) {
    WG_LOAD(kk + 32, 1);
    WG_MM(0);
    int kn = (kk + 64 < K) ? (kk + 64) : 0;  // dummy reload on last iter
    WG_LOAD(kn, 0);
    WG_MM(1);
  }
#undef WG_LOAD
#undef WG_MM
}

#define ACC_DECL(N16V)                                \
  f32x4 acc[4][N16V];                                 \
  { f32x4 z = {0.f, 0.f, 0.f, 0.f};                   \
    for (int i = 0; i < 4; ++i)                       \
      for (int j = 0; j < N16V; ++j) acc[i][j] = z; }

#define IDX_DECL                                      \
  const int tid = threadIdx.x;                        \
  const int wave = tid >> 6;                          \
  const int lane = tid & 63;                          \
  const int quad = lane >> 4;                         \
  const int l16 = lane & 15;                          \
  (void)lane;

// ---------------------------------------------------------------------------
// K1: carry (with bool-layout detection), x gather (fp32 out + bf16), h->bf16
// ---------------------------------------------------------------------------
__global__ void k_prep(const int* __restrict__ ids, const void* __restrict__ mask,
                       const float* __restrict__ emb, const float* __restrict__ hstate,
                       float* __restrict__ xout, u16* __restrict__ x_bf,
                       u16* __restrict__ h_bf, float* __restrict__ carry)
{
  __shared__ int sInt;
  const int tid = threadIdx.x, s = blockIdx.x;
  if (tid == 0) sInt = 1;
  __syncthreads();
  if (tid < 64) {
    int v = ((const int*)mask)[tid];
    if (v != 0 && v != 1) atomicAnd(&sInt, 0);
  }
  __syncthreads();
  if (tid == 0) {
    int m = sInt ? ((const int*)mask)[s] : (int)((const unsigned char*)mask)[s];
    carry[s] = m ? 0.0f : 1.0f;
  }
  long id = ids[s];
  int k = tid * 4;
  float4 v = *(const float4*)(emb + id * DIM + k);
  *(float4*)(xout + (long)s * DIM + k) = v;
  ushort4 h; h.x = f2bf(v.x); h.y = f2bf(v.y); h.z = f2bf(v.z); h.w = f2bf(v.w);
  *(ushort4*)(x_bf + (long)s * DIM + k) = h;
#pragma unroll
  for (int l = 0; l < NL; ++l) {
    long off = (long)l * BSZ * DIM + (long)s * DIM + k;
    float4 w = *(const float4*)(hstate + off);
    ushort4 o; o.x = f2bf(w.x); o.y = f2bf(w.y); o.z = f2bf(w.z); o.w = f2bf(w.w);
    *(ushort4*)(h_bf + off) = o;
  }
}

// ---------------------------------------------------------------------------
// K2: [alpha_pre | x_proj] = x @ [W_alpha ; W_in]^T, fused wm_new epilogue
// 64 blocks: n-tile 32 each (first 32 blocks alpha, next 32 x_proj)
// ---------------------------------------------------------------------------
__global__ void k_gemm1(const u16* __restrict__ x_bf,
                        const float* __restrict__ W_alpha, const float* __restrict__ W_in,
                        const float* __restrict__ carry, const float* __restrict__ wm_state,
                        const float* __restrict__ xout,
                        u16* __restrict__ wm_bf, u16* __restrict__ cur_bf)
{
  IDX_DECL
  ACC_DECL(2)
  int n0g = blockIdx.x * 32;
  bool isAlpha = (n0g < DIM);
  int n0 = isAlpha ? n0g : n0g - DIM;
  const float* B = (isAlpha ? W_alpha : W_in) + (long)n0 * DIM;
  wave_gemm<4, 2, DIM, false>(x_bf + (long)wave * 64 * DIM, DIM, B, DIM, 0, acc);
#pragma unroll
  for (int mi = 0; mi < 4; ++mi)
#pragma unroll
    for (int ni = 0; ni < 2; ++ni) {
      int n = n0 + ni * 16 + l16;
#pragma unroll
      for (int r = 0; r < 4; ++r) {
        int s = wave * 64 + mi * 16 + quad * 4 + r;
        float c = acc[mi][ni][r];
        long idx = (long)s * DIM + n;
        if (isAlpha) {
          wm_bf[idx] = f2bf(carry[s] * sigm(c) * wm_state[idx] + xout[idx]);
        } else {
          cur_bf[idx] = f2bf(c);
        }
      }
    }
}

// ---------------------------------------------------------------------------
// K3: y_wm = tanh(wm_new @ W_wm_out^T)   (32 blocks, n-tile 32)
// ---------------------------------------------------------------------------
__global__ void k_gemm2(const u16* __restrict__ wm_bf, const float* __restrict__ W_wm_out,
                        float* __restrict__ yout, u16* __restrict__ ywm_bf)
{
  IDX_DECL
  ACC_DECL(2)
  int n0 = blockIdx.x * 32;
  wave_gemm<4, 2, DIM, false>(wm_bf + (long)wave * 64 * DIM, DIM,
                              W_wm_out + (long)n0 * DIM, DIM, 0, acc);
#pragma unroll
  for (int mi = 0; mi < 4; ++mi)
#pragma unroll
    for (int ni = 0; ni < 2; ++ni) {
      int n = n0 + ni * 16 + l16;
#pragma unroll
      for (int r = 0; r < 4; ++r) {
        int s = wave * 64 + mi * 16 + quad * 4 + r;
        float y = tanhf(acc[mi][ni][r]);
        long idx = (long)s * DIM + n;
        yout[idx] = y;
        ywm_bf[idx] = f2bf(y);
      }
    }
}

// ---------------------------------------------------------------------------
// K4/K6: a = cur@W_x^T + h@W_h^T + y_wm@W_wml^T   (32 blocks: 8 b x 4 n-tiles)
// ---------------------------------------------------------------------------
__global__ void k_gemm_a(int l, const u16* __restrict__ cur_bf, const u16* __restrict__ h_bf,
                         const u16* __restrict__ ywm_bf,
                         const float* __restrict__ W_x, const float* __restrict__ W_h,
                         const float* __restrict__ W_wml,
                         float* __restrict__ a_f32, u16* __restrict__ a_bf)
{
  IDX_DECL
  ACC_DECL(2)
  int b = blockIdx.x >> 2;
  int n0 = (blockIdx.x & 3) * 32;
  const u16* Ac = cur_bf + (long)wave * 64 * DIM + b * DH;
  const u16* Ah = h_bf + (long)l * BSZ * DIM + (long)wave * 64 * DIM + b * DH;
  const u16* Ay = ywm_bf + (long)wave * 64 * DIM;
  wave_gemm<4, 2, DH, false>(Ac, DIM, W_x + ((long)(l * NB + b) * DH + n0) * DH, DH, 0, acc);
  wave_gemm<4, 2, DH, false>(Ah, DIM, W_h + ((long)(l * NB + b) * DH + n0) * DH, DH, 0, acc);
  wave_gemm<4, 2, DIM, false>(Ay, DIM, W_wml + ((long)(l * NB + b) * DH + n0) * DIM, DIM, 0, acc);
#pragma unroll
  for (int mi = 0; mi < 4; ++mi)
#pragma unroll
    for (int ni = 0; ni < 2; ++ni) {
      int e = n0 + ni * 16 + l16;
#pragma unroll
      for (int r = 0; r < 4; ++r) {
        int s = wave * 64 + mi * 16 + quad * 4 + r;
        float c = acc[mi][ni][r];
        long idx = (long)s * DIM + b * DH + e;
        a_f32[idx] = c;
        a_bf[idx] = f2bf(c);
      }
    }
}

// ---------------------------------------------------------------------------
// K5/K7: g = sigmoid(a@W_g^T + surprise*w_s + b_g); h_new gating
// ---------------------------------------------------------------------------
__global__ void k_gemm_g(int l, const u16* __restrict__ a_bf, const float* __restrict__ W_g,
                         const float* __restrict__ w_s, const float* __restrict__ b_g,
                         const float* __restrict__ surprise, const float* __restrict__ carry,
                         const float* __restrict__ hstate, const float* __restrict__ a_f32,
                         u16* __restrict__ hout_bf)
{
  IDX_DECL
  ACC_DECL(2)
  int b = blockIdx.x >> 2;
  int n0 = (blockIdx.x & 3) * 32;
  wave_gemm<4, 2, DH, false>(a_bf + (long)wave * 64 * DIM + b * DH, DIM,
                             W_g + ((long)(l * NB + b) * DH + n0) * DH, DH, 0, acc);
#pragma unroll
  for (int mi = 0; mi < 4; ++mi)
#pragma unroll
    for (int ni = 0; ni < 2; ++ni) {
      int e = n0 + ni * 16 + l16;
#pragma unroll
      for (int r = 0; r < 4; ++r) {
        int s = wave * 64 + mi * 16 + quad * 4 + r;
        float c = acc[mi][ni][r];
        long idx = (long)s * DIM + b * DH + e;
        float gp = c + surprise[s] * w_s[(l * NB + b) * DH + e] + b_g[(l * NB + b) * DH + e];
        float g = sigm(gp);
        float ho = hstate[(long)l * BSZ * DIM + idx];
        float hn = carry[s] * ((1.0f - g) * ho + g * tanhf(a_f32[idx]));
        hout_bf[idx] = f2bf(hn);
      }
    }
}

// ---------------------------------------------------------------------------
// K8: logits = h_final @ emb^T   (786 blocks, n-tile 64, HBM-bound)
// ---------------------------------------------------------------------------
__global__ void k_logits(const u16* __restrict__ hfin_bf, const float* __restrict__ emb,
                         float* __restrict__ out)
{
  IDX_DECL
  ACC_DECL(4)
  int n0 = blockIdx.x * 64;
  wave_gemm<4, 4, DIM, true>(hfin_bf + (long)wave * 64 * DIM, DIM,
                             emb + (long)n0 * DIM, DIM, VOC - 1 - n0, acc);
#pragma unroll
  for (int mi = 0; mi < 4; ++mi)
#pragma unroll
    for (int ni = 0; ni < 4; ++ni) {
      int n = n0 + ni * 16 + l16;
      if (n < VOC) {
#pragma unroll
        for (int r = 0; r < 4; ++r) {
          int s = wave * 64 + mi * 16 + quad * 4 + r;
          out[(long)s * VOC + n] = acc[mi][ni][r];
        }
      }
    }
}

extern "C" void kernel_launch(void* const* d_in, const int* in_sizes, int n_in,
                              void* d_out, int out_size, void* d_ws, size_t ws_size,
                              hipStream_t stream) {
  const int*   input_id = (const int*)d_in[0];
  const void*  reset    = d_in[1];
  const float* surprise = (const float*)d_in[2];
  const float* wm_state = (const float*)d_in[3];
  const float* h_state  = (const float*)d_in[4];
  const float* emb      = (const float*)d_in[5];
  const float* W_in     = (const float*)d_in[6];
  const float* W_alpha  = (const float*)d_in[7];
  const float* W_wm_out = (const float*)d_in[8];
  const float* W_x      = (const float*)d_in[9];
  const float* W_h      = (const float*)d_in[10];
  const float* W_wml    = (const float*)d_in[11];
  const float* W_g      = (const float*)d_in[12];
  const float* w_s      = (const float*)d_in[13];
  const float* b_g      = (const float*)d_in[14];

  float* out  = (float*)d_out;
  float* xout = out + (size_t)BSZ * VOC;          // x output (fp32, exact)
  float* yout = xout + (size_t)BSZ * DIM;         // y_wm output

  // Scratch lives in the logits region of d_out (only read before k_logits).
  const long SD = (long)BSZ * DIM;                // 262144
  u16* scr    = (u16*)d_out;
  u16* x_bf   = scr;                              // 256x1024
  u16* wm_bf  = scr + SD;
  u16* cur_bf = scr + 2 * SD;
  u16* ywm_bf = scr + 3 * SD;
  u16* h_bf   = scr + 4 * SD;                     // 2x256x1024
  u16* a_bf   = scr + 6 * SD;
  float* a_f32 = (float*)(scr + 8 * SD);          // 256x1024 fp32

  // h_final + carry live OUTSIDE d_out (read while k_logits writes d_out)
  float* carry  = (float*)d_ws;
  u16* hfin_bf  = (u16*)((char*)d_ws + 1024);

  k_prep<<<BSZ, 256, 0, stream>>>(input_id, reset, emb, h_state, xout, x_bf, h_bf, carry);
  k_gemm1<<<64, 256, 0, stream>>>(x_bf, W_alpha, W_in, carry, wm_state, xout, wm_bf, cur_bf);
  k_gemm2<<<32, 256, 0, stream>>>(wm_bf, W_wm_out, yout, ywm_bf);
  k_gemm_a<<<32, 256, 0, stream>>>(0, cur_bf, h_bf, ywm_bf, W_x, W_h, W_wml, a_f32, a_bf);
  k_gemm_g<<<32, 256, 0, stream>>>(0, a_bf, W_g, w_s, b_g, surprise, carry, h_state, a_f32, cur_bf);
  k_gemm_a<<<32, 256, 0, stream>>>(1, cur_bf, h_bf, ywm_bf, W_x, W_h, W_wml, a_f32, a_bf);
  k_gemm_g<<<32, 256, 0, stream>>>(1, a_bf, W_g, w_s, b_g, surprise, carry, h_state, a_f32, hfin_bf);
  k_logits<<<(VOC + 63) / 64, 256, 0, stream>>>(hfin_bf, emb, out);
}

// Round 3
// 588.520 us; speedup vs baseline: 1.6632x; 1.6632x over previous
//
#include <hip/hip_runtime.h>
#include <math.h>

#define BSZ 256
#define DIM 1024
#define VOC 50257
#define NL 2
#define NB 8
#define DH 128

typedef __bf16 bf16x8 __attribute__((ext_vector_type(8)));
typedef float  f32x4  __attribute__((ext_vector_type(4)));
typedef unsigned short u16;
typedef u16 u16x8 __attribute__((ext_vector_type(8)));

__device__ __forceinline__ u16 f2bf(float f) {
  unsigned int u = __float_as_uint(f);
  u += 0x7fffu + ((u >> 16) & 1u);   // RNE
  return (u16)(u >> 16);
}
__device__ __forceinline__ float sigm(float x) { return 1.0f / (1.0f + __expf(-x)); }

// ---------------------------------------------------------------------------
// Barrier-free per-wave GEMM: acc[M16][N16] += A(bf16, row-major lda) *
// B(fp32, row-major ldb)^T. Fragments loaded directly from global in MFMA
// operand layout; peeled 2-stage register double-buffer (no LDS, no barriers).
// ---------------------------------------------------------------------------
template<int M16, int N16, int K, bool CLAMPN>
__device__ __forceinline__ void wave_gemm(
    const u16* __restrict__ A, int lda,
    const float* __restrict__ B, int ldb, int nClamp,
    f32x4 (&acc)[M16][N16])
{
  const int lane = threadIdx.x & 63;
  const int quad = lane >> 4;
  const int l16  = lane & 15;

  const u16* aR[M16];
  const float* bR[N16];
#pragma unroll
  for (int mi = 0; mi < M16; ++mi)
    aR[mi] = A + (long)(mi * 16 + l16) * lda + quad * 8;
#pragma unroll
  for (int ni = 0; ni < N16; ++ni) {
    int n = ni * 16 + l16;
    if (CLAMPN) n = n > nClamp ? nClamp : n;   // clamp addr; result discarded
    bR[ni] = B + (long)n * ldb + quad * 8;
  }

  bf16x8 aF[2][M16];
  bf16x8 bF[2][N16];

#define WG_LOAD(kk, buf)                                                  \
  {                                                                       \
    _Pragma("unroll")                                                     \
    for (int ni = 0; ni < N16; ++ni) {                                    \
      float4 v0 = *(const float4*)(bR[ni] + (kk));                        \
      float4 v1 = *(const float4*)(bR[ni] + (kk) + 4);                    \
      u16x8 h;                                                            \
      h[0] = f2bf(v0.x); h[1] = f2bf(v0.y);                               \
      h[2] = f2bf(v0.z); h[3] = f2bf(v0.w);                               \
      h[4] = f2bf(v1.x); h[5] = f2bf(v1.y);                               \
      h[6] = f2bf(v1.z); h[7] = f2bf(v1.w);                               \
      bF[buf][ni] = __builtin_bit_cast(bf16x8, h);                        \
    }                                                                     \
    _Pragma("unroll")                                                     \
    for (int mi = 0; mi < M16; ++mi)                                      \
      aF[buf][mi] = *(const bf16x8*)(aR[mi] + (kk));                      \
  }

#define WG_MM(buf)                                                        \
  {                                                                       \
    _Pragma("unroll")                                                     \
    for (int mi = 0; mi < M16; ++mi)                                      \
      _Pragma("unroll")                                                   \
      for (int ni = 0; ni < N16; ++ni)                                    \
        acc[mi][ni] = __builtin_amdgcn_mfma_f32_16x16x32_bf16(            \
            aF[buf][mi], bF[buf][ni], acc[mi][ni], 0, 0, 0);              \
  }

  WG_LOAD(0, 0);
#pragma unroll 1
  for (int kk = 0; kk < K - 64; kk += 64) {
    WG_LOAD(kk + 32, 1);
    WG_MM(0);
    WG_LOAD(kk + 64, 0);
    WG_MM(1);
  }
  WG_LOAD(K - 32, 1);
  WG_MM(0);
  WG_MM(1);
#undef WG_LOAD
#undef WG_MM
}

#define ACC_DECL(N16V)                                \
  f32x4 acc[4][N16V];                                 \
  { f32x4 z = {0.f, 0.f, 0.f, 0.f};                   \
    _Pragma("unroll")                                 \
    for (int i = 0; i < 4; ++i)                       \
      _Pragma("unroll")                               \
      for (int j = 0; j < N16V; ++j) acc[i][j] = z; }

// ---------------------------------------------------------------------------
// K1: carry (bool-layout detect), x gather, h->bf16, + LLC warm of all weights
// ---------------------------------------------------------------------------
__global__ __launch_bounds__(256) void k_prep(
    const int* __restrict__ ids, const void* __restrict__ mask,
    const float* __restrict__ emb, const float* __restrict__ hstate,
    const float* __restrict__ W_alpha, const float* __restrict__ W_in,
    const float* __restrict__ W_wm_out, const float* __restrict__ W_x,
    const float* __restrict__ W_h, const float* __restrict__ W_wml,
    const float* __restrict__ W_g,
    float* __restrict__ xout, u16* __restrict__ x_bf,
    u16* __restrict__ h_bf, float* __restrict__ carry, float* __restrict__ sink)
{
  __shared__ int sInt;
  const int tid = threadIdx.x, s = blockIdx.x;
  if (tid == 0) sInt = 1;
  __syncthreads();
  if (tid < 64) {
    int v = ((const int*)mask)[tid];
    if (v != 0 && v != 1) atomicAnd(&sInt, 0);
  }
  __syncthreads();
  if (tid == 0) {
    int m = sInt ? ((const int*)mask)[s] : (int)((const unsigned char*)mask)[s];
    carry[s] = m ? 0.0f : 1.0f;
  }
  long id = ids[s];
  int k = tid * 4;
  float4 v = *(const float4*)(emb + id * DIM + k);
  *(float4*)(xout + (long)s * DIM + k) = v;
  ushort4 h; h.x = f2bf(v.x); h.y = f2bf(v.y); h.z = f2bf(v.z); h.w = f2bf(v.w);
  *(ushort4*)(x_bf + (long)s * DIM + k) = h;
#pragma unroll
  for (int l = 0; l < NL; ++l) {
    long off = (long)l * BSZ * DIM + (long)s * DIM + k;
    float4 w = *(const float4*)(hstate + off);
    ushort4 o; o.x = f2bf(w.x); o.y = f2bf(w.y); o.z = f2bf(w.z); o.w = f2bf(w.w);
    *(ushort4*)(h_bf + off) = o;
  }
  // ---- LLC warm (loads can't be eliminated; branch never taken) ----
  long gtid = (long)blockIdx.x * 256 + tid;
  long gstride = (long)gridDim.x * 256;
  float acc = 0.f;
  {
    const long nDD = (long)DIM * DIM / 4;       // 1024x1024 f32 -> float4 count
    for (long i = gtid; i < nDD; i += gstride) {
      float4 a = ((const float4*)W_alpha)[i];
      float4 b = ((const float4*)W_in)[i];
      float4 c = ((const float4*)W_wm_out)[i];
      acc += a.x + a.w + b.x + b.w + c.x + c.w;
    }
    const long nS = (long)NL * NB * DH * DH / 4;
    for (long i = gtid; i < nS; i += gstride) {
      float4 a = ((const float4*)W_x)[i];
      float4 b = ((const float4*)W_h)[i];
      float4 c = ((const float4*)W_g)[i];
      acc += a.x + a.w + b.x + b.w + c.x + c.w;
    }
    const long nW = (long)NL * NB * DH * DIM / 4;
    for (long i = gtid; i < nW; i += gstride) {
      float4 a = ((const float4*)W_wml)[i];
      acc += a.x + a.w;
    }
  }
  if (acc == -1.17521e35f) *sink = acc;   // never true in practice; defeats DCE
}

// ---------------------------------------------------------------------------
// K2: [alpha_pre | x_proj] = x @ [W_alpha ; W_in]^T, fused wm_new epilogue
// 512 blocks x 64 threads: m-slice = blk&3, n-tile16 = blk>>2 (128 tiles)
// ---------------------------------------------------------------------------
__global__ __launch_bounds__(64) void k_gemm1(
    const u16* __restrict__ x_bf,
    const float* __restrict__ W_alpha, const float* __restrict__ W_in,
    const float* __restrict__ carry, const float* __restrict__ wm_state,
    const float* __restrict__ xout,
    u16* __restrict__ wm_bf, u16* __restrict__ cur_bf)
{
  const int tid = threadIdx.x, quad = tid >> 4, l16 = tid & 15;
  const int m = blockIdx.x & 3;
  const int nt = blockIdx.x >> 2;
  const bool isAlpha = nt < 64;
  const int n0 = (isAlpha ? nt : nt - 64) * 16;
  ACC_DECL(1)
  wave_gemm<4, 1, DIM, false>(x_bf + (long)m * 64 * DIM, DIM,
                              (isAlpha ? W_alpha : W_in) + (long)n0 * DIM, DIM, 0, acc);
#pragma unroll
  for (int mi = 0; mi < 4; ++mi) {
    int n = n0 + l16;
#pragma unroll
    for (int r = 0; r < 4; ++r) {
      int s = m * 64 + mi * 16 + quad * 4 + r;
      float c = acc[mi][0][r];
      long idx = (long)s * DIM + n;
      if (isAlpha) wm_bf[idx] = f2bf(carry[s] * sigm(c) * wm_state[idx] + xout[idx]);
      else         cur_bf[idx] = f2bf(c);
    }
  }
}

// ---------------------------------------------------------------------------
// K3: y_wm = tanh(wm_new @ W_wm_out^T)   (256 blocks x 64 threads)
// ---------------------------------------------------------------------------
__global__ __launch_bounds__(64) void k_gemm2(
    const u16* __restrict__ wm_bf, const float* __restrict__ W_wm_out,
    float* __restrict__ yout, u16* __restrict__ ywm_bf)
{
  const int tid = threadIdx.x, quad = tid >> 4, l16 = tid & 15;
  const int m = blockIdx.x & 3;
  const int n0 = (blockIdx.x >> 2) * 16;
  ACC_DECL(1)
  wave_gemm<4, 1, DIM, false>(wm_bf + (long)m * 64 * DIM, DIM,
                              W_wm_out + (long)n0 * DIM, DIM, 0, acc);
#pragma unroll
  for (int mi = 0; mi < 4; ++mi) {
    int n = n0 + l16;
#pragma unroll
    for (int r = 0; r < 4; ++r) {
      int s = m * 64 + mi * 16 + quad * 4 + r;
      float y = tanhf(acc[mi][0][r]);
      long idx = (long)s * DIM + n;
      yout[idx] = y;
      ywm_bf[idx] = f2bf(y);
    }
  }
}

// ---------------------------------------------------------------------------
// K4/K6: a = cur@W_x^T + h@W_h^T + y_wm@W_wml^T
// 256 blocks x 64 threads: m = blk&3, nt = blk>>2 (64 e-tiles: b = nt>>3)
// ---------------------------------------------------------------------------
__global__ __launch_bounds__(64) void k_gemm_a(
    int l, const u16* __restrict__ cur_bf, const u16* __restrict__ h_bf,
    const u16* __restrict__ ywm_bf,
    const float* __restrict__ W_x, const float* __restrict__ W_h,
    const float* __restrict__ W_wml,
    float* __restrict__ a_f32, u16* __restrict__ a_bf)
{
  const int tid = threadIdx.x, quad = tid >> 4, l16 = tid & 15;
  const int m = blockIdx.x & 3;
  const int nt = blockIdx.x >> 2;
  const int b = nt >> 3;
  const int e0 = (nt & 7) * 16;
  ACC_DECL(1)
  const long moff = (long)m * 64 * DIM;
  wave_gemm<4, 1, DH, false>(cur_bf + moff + b * DH, DIM,
                             W_x + ((long)(l * NB + b) * DH + e0) * DH, DH, 0, acc);
  wave_gemm<4, 1, DH, false>(h_bf + (long)l * BSZ * DIM + moff + b * DH, DIM,
                             W_h + ((long)(l * NB + b) * DH + e0) * DH, DH, 0, acc);
  wave_gemm<4, 1, DIM, false>(ywm_bf + moff, DIM,
                              W_wml + ((long)(l * NB + b) * DH + e0) * DIM, DIM, 0, acc);
#pragma unroll
  for (int mi = 0; mi < 4; ++mi) {
    int e = e0 + l16;
#pragma unroll
    for (int r = 0; r < 4; ++r) {
      int s = m * 64 + mi * 16 + quad * 4 + r;
      float c = acc[mi][0][r];
      long idx = (long)s * DIM + b * DH + e;
      a_f32[idx] = c;
      a_bf[idx] = f2bf(c);
    }
  }
}

// ---------------------------------------------------------------------------
// K5/K7: g = sigmoid(a@W_g^T + surprise*w_s + b_g); h_new gating
// ---------------------------------------------------------------------------
__global__ __launch_bounds__(64) void k_gemm_g(
    int l, const u16* __restrict__ a_bf, const float* __restrict__ W_g,
    const float* __restrict__ w_s, const float* __restrict__ b_g,
    const float* __restrict__ surprise, const float* __restrict__ carry,
    const float* __restrict__ hstate, const float* __restrict__ a_f32,
    u16* __restrict__ hout_bf)
{
  const int tid = threadIdx.x, quad = tid >> 4, l16 = tid & 15;
  const int m = blockIdx.x & 3;
  const int nt = blockIdx.x >> 2;
  const int b = nt >> 3;
  const int e0 = (nt & 7) * 16;
  ACC_DECL(1)
  wave_gemm<4, 1, DH, false>(a_bf + (long)m * 64 * DIM + b * DH, DIM,
                             W_g + ((long)(l * NB + b) * DH + e0) * DH, DH, 0, acc);
#pragma unroll
  for (int mi = 0; mi < 4; ++mi) {
    int e = e0 + l16;
#pragma unroll
    for (int r = 0; r < 4; ++r) {
      int s = m * 64 + mi * 16 + quad * 4 + r;
      float c = acc[mi][0][r];
      long idx = (long)s * DIM + b * DH + e;
      float gp = c + surprise[s] * w_s[(l * NB + b) * DH + e] + b_g[(l * NB + b) * DH + e];
      float g = sigm(gp);
      float ho = hstate[(long)l * BSZ * DIM + idx];
      float hn = carry[s] * ((1.0f - g) * ho + g * tanhf(a_f32[idx]));
      hout_bf[idx] = f2bf(hn);
    }
  }
}

// ---------------------------------------------------------------------------
// K8: logits = h_final @ emb^T  (1571 blocks x 256 threads, n-tile 32)
// ---------------------------------------------------------------------------
__global__ __launch_bounds__(256) void k_logits(
    const u16* __restrict__ hfin_bf, const float* __restrict__ emb,
    float* __restrict__ out)
{
  const int tid = threadIdx.x;
  const int wave = tid >> 6;
  const int quad = (tid >> 4) & 3;
  const int l16 = tid & 15;
  ACC_DECL(2)
  int n0 = blockIdx.x * 32;
  wave_gemm<4, 2, DIM, true>(hfin_bf + (long)wave * 64 * DIM, DIM,
                             emb + (long)n0 * DIM, DIM, VOC - 1 - n0, acc);
#pragma unroll
  for (int mi = 0; mi < 4; ++mi)
#pragma unroll
    for (int ni = 0; ni < 2; ++ni) {
      int n = n0 + ni * 16 + l16;
      if (n < VOC) {
#pragma unroll
        for (int r = 0; r < 4; ++r) {
          int s = wave * 64 + mi * 16 + quad * 4 + r;
          out[(long)s * VOC + n] = acc[mi][ni][r];
        }
      }
    }
}

extern "C" void kernel_launch(void* const* d_in, const int* in_sizes, int n_in,
                              void* d_out, int out_size, void* d_ws, size_t ws_size,
                              hipStream_t stream) {
  const int*   input_id = (const int*)d_in[0];
  const void*  reset    = d_in[1];
  const float* surprise = (const float*)d_in[2];
  const float* wm_state = (const float*)d_in[3];
  const float* h_state  = (const float*)d_in[4];
  const float* emb      = (const float*)d_in[5];
  const float* W_in     = (const float*)d_in[6];
  const float* W_alpha  = (const float*)d_in[7];
  const float* W_wm_out = (const float*)d_in[8];
  const float* W_x      = (const float*)d_in[9];
  const float* W_h      = (const float*)d_in[10];
  const float* W_wml    = (const float*)d_in[11];
  const float* W_g      = (const float*)d_in[12];
  const float* w_s      = (const float*)d_in[13];
  const float* b_g      = (const float*)d_in[14];

  float* out  = (float*)d_out;
  float* xout = out + (size_t)BSZ * VOC;          // x output (fp32, exact)
  float* yout = xout + (size_t)BSZ * DIM;         // y_wm output

  // Scratch lives in the logits region of d_out (only read before k_logits).
  const long SD = (long)BSZ * DIM;                // 262144
  u16* scr    = (u16*)d_out;
  u16* x_bf   = scr;                              // 256x1024
  u16* wm_bf  = scr + SD;
  u16* cur_bf = scr + 2 * SD;
  u16* ywm_bf = scr + 3 * SD;
  u16* h_bf   = scr + 4 * SD;                     // 2x256x1024
  u16* a_bf   = scr + 6 * SD;
  float* a_f32 = (float*)(scr + 8 * SD);          // 256x1024 fp32

  // h_final + carry live OUTSIDE d_out (read while k_logits writes d_out)
  float* carry  = (float*)d_ws;
  u16* hfin_bf  = (u16*)((char*)d_ws + 1024);
  float* sink   = (float*)((char*)d_ws + 600 * 1024);

  k_prep<<<BSZ, 256, 0, stream>>>(input_id, reset, emb, h_state,
                                  W_alpha, W_in, W_wm_out, W_x, W_h, W_wml, W_g,
                                  xout, x_bf, h_bf, carry, sink);
  k_gemm1<<<512, 64, 0, stream>>>(x_bf, W_alpha, W_in, carry, wm_state, xout, wm_bf, cur_bf);
  k_gemm2<<<256, 64, 0, stream>>>(wm_bf, W_wm_out, yout, ywm_bf);
  k_gemm_a<<<256, 64, 0, stream>>>(0, cur_bf, h_bf, ywm_bf, W_x, W_h, W_wml, a_f32, a_bf);
  k_gemm_g<<<256, 64, 0, stream>>>(0, a_bf, W_g, w_s, b_g, surprise, carry, h_state, a_f32, cur_bf);
  k_gemm_a<<<256, 64, 0, stream>>>(1, cur_bf, h_bf, ywm_bf, W_x, W_h, W_wml, a_f32, a_bf);
  k_gemm_g<<<256, 64, 0, stream>>>(1, a_bf, W_g, w_s, b_g, surprise, carry, h_state, a_f32, hfin_bf);
  k_logits<<<(VOC + 31) / 32, 256, 0, stream>>>(hfin_bf, emb, out);
}